// Round 7
// baseline (578.484 us; speedup 1.0000x reference)
//
#include <hip/hip_runtime.h>
#include <hip/hip_bf16.h>
#include <math.h>

#define SEQ    2048
#define DIMN   1024
#define NHEAD  16
#define HDIM   64
#define BATCH  2
#define ROWS   4096
#define HIDDEN 2816
#define FCHUNK 2048
#define QKVS   3072       // interleaved QKV row stride

typedef __attribute__((ext_vector_type(8))) short short8;
typedef __attribute__((ext_vector_type(4))) float f32x4;
typedef unsigned short ushort_t;
typedef __attribute__((address_space(1))) void gas_t;
typedef __attribute__((address_space(3))) void las_t;

__device__ __forceinline__ float bfbits(ushort_t u){ return __uint_as_float(((unsigned)u) << 16); }
__device__ __forceinline__ ushort_t f2bu(float f){
  __hip_bfloat16 h = __float2bfloat16(f);
  return *reinterpret_cast<ushort_t*>(&h);
}
__device__ __forceinline__ ushort_t f2bu_t(float f){ return (ushort_t)(__float_as_uint(f) >> 16); }
__device__ __forceinline__ float ldv(const float* p){ return *p; }
__device__ __forceinline__ float ldv(const ushort_t* p){ return bfbits(*p); }
__device__ __forceinline__ void stv(float* p, float v){ *p = v; }
__device__ __forceinline__ void stv(ushort_t* p, float v){ *p = f2bu(v); }
__device__ __forceinline__ void async_cp16(const ushort_t* g, ushort_t* l){
  __builtin_amdgcn_global_load_lds((gas_t*)g, (las_t*)l, 16, 0, 0);
}
__device__ __forceinline__ ushort4 ld4u(const float* p){
  float4 v = *(const float4*)p;
  ushort4 u; u.x = f2bu(v.x); u.y = f2bu(v.y); u.z = f2bu(v.z); u.w = f2bu(v.w);
  return u;
}
__device__ __forceinline__ ushort4 ld4u(const ushort_t* p){ return *(const ushort4*)p; }

// ---------------- t = silu(adafm_input) @ proj_w + proj_b ----------------
__global__ void k_time(const float* __restrict__ ada, const float* __restrict__ pw,
                       const float* __restrict__ pb, float* __restrict__ t){
  int b = blockIdx.x >> 9, o = blockIdx.x & 511, lane = threadIdx.x;
  float acc = 0.f;
  for(int i = lane; i < DIMN; i += 64){
    float a = ada[b*DIMN + i];
    float s = a / (1.f + expf(-a));
    acc += s * pw[i*512 + o];
  }
  for(int off = 32; off; off >>= 1) acc += __shfl_down(acc, off);
  if(lane == 0) t[b*512 + o] = acc + pb[o];
}

// ---------------- fused: g_wb[n] then circulant pack Gpk[wb][kc][n][mm] ----------------
__global__ void k_gp(const float* __restrict__ t, ushort_t* __restrict__ Gpk){
  __shared__ float gl[256];
  int wb = blockIdx.x, kc = blockIdx.y, tid = threadIdx.x;
  int b = wb & 1, which = wb >> 1;
  const float C = 6.283185307179586f / 256.f;
  float acc = 0.f;
  for(int k = 0; k < 256; k++){
    float f = t[b*512 + which*256 + k];
    acc += f * cosf(C * (float)((k*tid) & 255));
  }
  gl[tid] = acc * (1.f/256.f);
  __syncthreads();
  ushort_t* ob = Gpk + ((size_t)(wb*8 + kc))*8192;
  for(int rep = 0; rep < 4; rep++){
    int n = rep*64 + (tid >> 2), mmb = (tid & 3)*8;
    short8 o;
    #pragma unroll
    for(int j = 0; j < 8; j++)
      o[j] = (short)f2bu(gl[(n - kc*32 - (mmb + j)) & 255]);
    *(short8*)(ob + n*32 + mmb) = o;
  }
}

// ---------------- MFMA modulate: per-patch circular conv as GEMM ----------------
#define APAD 264
#define GPAD 40
template<typename IN>
__global__ __launch_bounds__(256) void k_modmf(const IN* __restrict__ src,
        const ushort_t* __restrict__ Gpk, ushort_t* __restrict__ dst){
  __shared__ __align__(16) ushort_t Ap[64*APAD];
  __shared__ __align__(16) ushort_t Gs[128*GPAD];
  int nh = blockIdx.x, i = blockIdx.y, b = blockIdx.z;
  int tid = threadIdx.x, lane = tid & 63, w = tid >> 6;
  int l15 = lane & 15, quad = lane >> 4;
  const IN* xb = src + (size_t)b*SEQ*DIMN + (size_t)(i*16)*DIMN;
  int j = tid >> 2, c = (tid & 3)*4;
  #pragma unroll 4
  for(int rep = 0; rep < 16; rep++){
    ushort4 v4 = ld4u(xb + (size_t)rep*DIMN + tid*4);
    *(ushort4*)&Ap[j*APAD + rep*16 + c] = v4;
  }
  f32x4 acc[8];
  #pragma unroll
  for(int nt = 0; nt < 8; nt++){ acc[nt][0]=0.f; acc[nt][1]=0.f; acc[nt][2]=0.f; acc[nt][3]=0.f; }
  for(int kc = 0; kc < 8; kc++){
    __syncthreads();
    {
      const ushort_t* gsrc = Gpk + ((size_t)(b*8 + kc))*8192 + nh*4096;
      #pragma unroll
      for(int r2 = 0; r2 < 2; r2++){
        int n = r2*64 + (tid >> 2), mm = (tid & 3)*8;
        *(short8*)&Gs[n*GPAD + mm] = *(const short8*)(gsrc + r2*2048 + tid*8);
      }
    }
    __syncthreads();
    short8 af = *(const short8*)&Ap[(w*16 + l15)*APAD + kc*32 + quad*8];
    #pragma unroll
    for(int nt = 0; nt < 8; nt++){
      short8 bf = *(const short8*)&Gs[(nt*16 + l15)*GPAD + quad*8];
      acc[nt] = __builtin_amdgcn_mfma_f32_16x16x32_bf16(af, bf, acc[nt], 0, 0, 0);
    }
  }
  size_t ob = (size_t)b*SEQ*DIMN + (size_t)(i*16 + nh*8)*DIMN + (w*16 + quad*4)*16 + l15;
  #pragma unroll
  for(int nt = 0; nt < 8; nt++)
    #pragma unroll
    for(int t = 0; t < 4; t++)
      dst[ob + (size_t)nt*DIMN + t*16] = f2bu(acc[nt][t]);
}

// ---------------- weight transpose: fp32 W[K][N] -> bf16 Wt[N][K] ----------------
__global__ void k_wt(const float* __restrict__ W, ushort_t* __restrict__ Wt, int K, int N){
  __shared__ float tile[32][33];
  int k0 = blockIdx.y*32, n0 = blockIdx.x*32;
  int r = threadIdx.x >> 3, c4 = (threadIdx.x & 7)*4;
  float4 v = *(const float4*)(W + (size_t)(k0 + r)*N + n0 + c4);
  tile[r][c4+0] = v.x; tile[r][c4+1] = v.y; tile[r][c4+2] = v.z; tile[r][c4+3] = v.w;
  __syncthreads();
  ushort4 o;
  o.x = f2bu(tile[c4+0][r]); o.y = f2bu(tile[c4+1][r]);
  o.z = f2bu(tile[c4+2][r]); o.w = f2bu(tile[c4+3][r]);
  *(ushort4*)(Wt + (size_t)(n0 + r)*K + k0 + c4) = o;
}

// ---------------- m97-style MFMA GEMM: C(MxN) = A(MxK) @ Wt(NxK)^T ----------------
template<int BM, int BN, typename OUT>
__global__ __launch_bounds__(256) void k_gemm_mf(const ushort_t* __restrict__ A,
        const ushort_t* __restrict__ Wt, OUT* __restrict__ C, int N, int K){
  constexpr int MT = BM/32, NT = BN/32;
  constexpr int AI = BM/64, BI = BN/64;
  __shared__ __align__(16) ushort_t As[BM*32];
  __shared__ __align__(16) ushort_t Bs[BN*32];
  int tid = threadIdx.x, lane = tid & 63, w = tid >> 6;
  int l15 = lane & 15, quad = lane >> 4;
  int m0 = blockIdx.y*BM, n0 = blockIdx.x*BN;
  int wr = (w>>1)*(BM/2), wc = (w&1)*(BN/2);
  int srow = lane >> 2, scol = (lane & 3)*8;
  const ushort_t* ag[AI]; ushort_t* al[AI];
  const ushort_t* bg[BI]; ushort_t* bl[BI];
  #pragma unroll
  for(int i = 0; i < AI; i++){
    int rb = w*AI + i;
    ag[i] = A + (size_t)(m0 + rb*16 + srow)*K + scol;
    al[i] = As + rb*512 + lane*8;
  }
  #pragma unroll
  for(int i = 0; i < BI; i++){
    int rb = w*BI + i;
    bg[i] = Wt + (size_t)(n0 + rb*16 + srow)*K + scol;
    bl[i] = Bs + rb*512 + lane*8;
  }
  f32x4 acc[MT][NT];
  #pragma unroll
  for(int mt = 0; mt < MT; mt++)
    #pragma unroll
    for(int nt = 0; nt < NT; nt++)
      for(int t = 0; t < 4; t++) acc[mt][nt][t] = 0.f;
  for(int kk = 0; kk < K; kk += 32){
    __syncthreads();
    #pragma unroll
    for(int i = 0; i < AI; i++) async_cp16(ag[i] + kk, al[i]);
    #pragma unroll
    for(int i = 0; i < BI; i++) async_cp16(bg[i] + kk, bl[i]);
    __syncthreads();
    short8 af[MT], bf[NT];
    #pragma unroll
    for(int mt = 0; mt < MT; mt++) af[mt] = *(const short8*)&As[(wr + mt*16 + l15)*32 + quad*8];
    #pragma unroll
    for(int nt = 0; nt < NT; nt++) bf[nt] = *(const short8*)&Bs[(wc + nt*16 + l15)*32 + quad*8];
    #pragma unroll
    for(int mt = 0; mt < MT; mt++)
      #pragma unroll
      for(int nt = 0; nt < NT; nt++)
        acc[mt][nt] = __builtin_amdgcn_mfma_f32_16x16x32_bf16(af[mt], bf[nt], acc[mt][nt], 0, 0, 0);
  }
  #pragma unroll
  for(int mt = 0; mt < MT; mt++)
    #pragma unroll
    for(int nt = 0; nt < NT; nt++)
      #pragma unroll
      for(int t = 0; t < 4; t++)
        stv(C + (size_t)(m0 + wr + mt*16 + quad*4 + t)*N + n0 + wc + nt*16 + l15, acc[mt][nt][t]);
}

// ---------------- fused FFN up: h = silu(A@w1 * sv*sqrt(H)) * (A@w3 * su) ----------------
__global__ __launch_bounds__(256) void k_ffn12(const ushort_t* __restrict__ A,
        const ushort_t* __restrict__ W1t, const ushort_t* __restrict__ W3t,
        const float* __restrict__ su, const float* __restrict__ sv,
        ushort_t* __restrict__ H, int K){
  __shared__ __align__(16) ushort_t As[128*32];
  __shared__ __align__(16) ushort_t B1s[64*32];
  __shared__ __align__(16) ushort_t B3s[64*32];
  int tid = threadIdx.x, lane = tid & 63, w = tid >> 6;
  int l15 = lane & 15, quad = lane >> 4;
  int m0 = blockIdx.y*128, n0 = blockIdx.x*64;
  int wr = (w>>1)*64, wc = (w&1)*32;
  int srow = lane >> 2, scol = (lane & 3)*8;
  const ushort_t* ag[2]; ushort_t* al[2];
  #pragma unroll
  for(int i = 0; i < 2; i++){
    int rb = w*2 + i;
    ag[i] = A + (size_t)(m0 + rb*16 + srow)*K + scol;
    al[i] = As + rb*512 + lane*8;
  }
  const ushort_t* b1g = W1t + (size_t)(n0 + w*16 + srow)*K + scol;
  const ushort_t* b3g = W3t + (size_t)(n0 + w*16 + srow)*K + scol;
  ushort_t* b1l = B1s + w*512 + lane*8;
  ushort_t* b3l = B3s + w*512 + lane*8;
  f32x4 acc1[4][2], acc3[4][2];
  #pragma unroll
  for(int mt = 0; mt < 4; mt++)
    #pragma unroll
    for(int nt = 0; nt < 2; nt++)
      for(int t = 0; t < 4; t++){ acc1[mt][nt][t] = 0.f; acc3[mt][nt][t] = 0.f; }
  for(int kk = 0; kk < K; kk += 32){
    __syncthreads();
    async_cp16(ag[0] + kk, al[0]);
    async_cp16(ag[1] + kk, al[1]);
    async_cp16(b1g + kk, b1l);
    async_cp16(b3g + kk, b3l);
    __syncthreads();
    short8 af[4], b1f[2], b3f[2];
    #pragma unroll
    for(int mt = 0; mt < 4; mt++) af[mt] = *(const short8*)&As[(wr + mt*16 + l15)*32 + quad*8];
    #pragma unroll
    for(int nt = 0; nt < 2; nt++){
      b1f[nt] = *(const short8*)&B1s[(wc + nt*16 + l15)*32 + quad*8];
      b3f[nt] = *(const short8*)&B3s[(wc + nt*16 + l15)*32 + quad*8];
    }
    #pragma unroll
    for(int mt = 0; mt < 4; mt++)
      #pragma unroll
      for(int nt = 0; nt < 2; nt++){
        acc1[mt][nt] = __builtin_amdgcn_mfma_f32_16x16x32_bf16(af[mt], b1f[nt], acc1[mt][nt], 0, 0, 0);
        acc3[mt][nt] = __builtin_amdgcn_mfma_f32_16x16x32_bf16(af[mt], b3f[nt], acc3[mt][nt], 0, 0, 0);
      }
  }
  #pragma unroll
  for(int nt = 0; nt < 2; nt++){
    int n = n0 + wc + nt*16 + l15;
    float svv = sv[n] * 53.06599665f, suv = su[n];
    #pragma unroll
    for(int mt = 0; mt < 4; mt++)
      #pragma unroll
      for(int t = 0; t < 4; t++){
        float hpre = acc1[mt][nt][t] * svv;
        float sil = hpre / (1.f + expf(-hpre));
        float hv = sil * (acc3[mt][nt][t] * suv);
        H[(size_t)(m0 + wr + mt*16 + quad*4 + t)*HIDDEN + n] = f2bu(hv);
      }
  }
}

// ---------------- rotary + justnorm + sqk scale, in place on interleaved QKV ----------------
__global__ void k_qkvprep(ushort_t* __restrict__ qkv, const float* __restrict__ fc,
        const float* __restrict__ fs, const float* __restrict__ sqk){
  int w = threadIdx.x >> 6, d = threadIdx.x & 63;
  int h = blockIdx.x*4 + w, s = blockIdx.y, b = blockIdx.z;
  size_t ib = ((size_t)(b*SEQ + s))*QKVS + h*HDIM + d;
  float q = bfbits(qkv[ib]), k = bfbits(qkv[ib + 1024]);
  float qn = __shfl_xor(q, 1), kn = __shfl_xor(k, 1);
  int p = d >> 1;
  float c = fc[s*32 + p], sn = fs[s*32 + p];
  float qr, kr;
  if((d & 1) == 0){ qr = q*c - qn*sn; kr = k*c - kn*sn; }
  else            { qr = qn*sn + q*c; kr = kn*sn + k*c; }
  float sq = qr*qr, sk = kr*kr;
  for(int off = 32; off; off >>= 1){ sq += __shfl_xor(sq, off); sk += __shfl_xor(sk, off); }
  float scl = sqk[h*HDIM + d] * 32.f;
  qkv[ib]        = f2bu(scl * qr / fmaxf(sqrtf(sq), 1e-12f));
  qkv[ib + 1024] = f2bu(scl * kr / fmaxf(sqrtf(sk), 1e-12f));
}

// ---------------- V transpose (from interleaved QKV) to [b][h][d][s] ----------------
__global__ void k_vt(const ushort_t* __restrict__ qkv, ushort_t* __restrict__ vto){
  __shared__ ushort_t tile[64][72];
  int s0 = blockIdx.x*64, h = blockIdx.y, b = blockIdx.z;
  int r = threadIdx.x >> 2, c = (threadIdx.x & 3)*16;
  const ushort_t* src = qkv + (size_t)(b*SEQ + s0 + r)*QKVS + 2048 + h*HDIM + c;
  *(short8*)&tile[r][c]     = *(const short8*)src;
  *(short8*)&tile[r][c + 8] = *(const short8*)(src + 8);
  __syncthreads();
  ushort_t* dst = vto + ((size_t)(b*NHEAD + h)*HDIM + r)*SEQ + s0 + c;
  for(int j = 0; j < 16; j += 4){
    ushort4 o;
    o.x = tile[c+j][r]; o.y = tile[c+j+1][r]; o.z = tile[c+j+2][r]; o.w = tile[c+j+3][r];
    *(ushort4*)(dst + j) = o;
  }
}

// ---------------- MFMA flash attention: 128 q-rows/block, fixed-max softmax ----------------
// grid (SEQ/128, NH, B), 4 waves; wave w handles q rows w*32..w*32+31 (qm=0,1 groups of 16).
#define LSTR 72
__global__ __launch_bounds__(256) void k_flash_mf(const ushort_t* __restrict__ qkv,
        const ushort_t* __restrict__ vt, ushort_t* __restrict__ out){
  int qb = blockIdx.x, h = blockIdx.y, b = blockIdx.z;
  int tid = threadIdx.x, lane = tid & 63, w = tid >> 6;
  int l15 = lane & 15, quad = lane >> 4;
  __shared__ __align__(16) ushort_t Ks[64*LSTR], Vts[64*LSTR];
  __shared__ __align__(16) ushort_t Ps[4][32*LSTR];
  size_t qkb = (size_t)b*SEQ*QKVS + h*HDIM;
  const ushort_t* vb = vt + (size_t)(b*NHEAD + h)*HDIM*SEQ;
  short8 qf[2][2];
  #pragma unroll
  for(int qm = 0; qm < 2; qm++){
    const ushort_t* qrow = qkv + qkb + (size_t)(qb*128 + w*32 + qm*16 + l15)*QKVS;
    qf[qm][0] = *(const short8*)(qrow + quad*8);
    qf[qm][1] = *(const short8*)(qrow + 32 + quad*8);
  }
  f32x4 o_acc[2][4];
  #pragma unroll
  for(int qm = 0; qm < 2; qm++)
    #pragma unroll
    for(int g = 0; g < 4; g++){ o_acc[qm][g][0]=0.f; o_acc[qm][g][1]=0.f; o_acc[qm][g][2]=0.f; o_acc[qm][g][3]=0.f; }
  float lsum[2] = {0.f, 0.f};
  int sr = tid >> 2, sc = tid & 3;
  const float C1 = 11.54156036f;   // 8*log2(e)
  const float C2 = 11.90223409f;   // 8.25*log2(e): scores provably < 8.04
  for(int ch = 0; ch < SEQ/64; ch++){
    __syncthreads();
    {
      const ushort_t* krow = qkv + qkb + (size_t)(b ? 0 : 0) + (size_t)(ch*64 + sr)*QKVS + 1024 + sc*16;
      short8 k0 = *(const short8*)krow, k1 = *(const short8*)(krow + 8);
      const ushort_t* vrow = vb + (size_t)sr*SEQ + ch*64 + sc*16;
      short8 v0 = *(const short8*)vrow, v1 = *(const short8*)(vrow + 8);
      *(short8*)&Ks[sr*LSTR + sc*16]      = k0;
      *(short8*)&Ks[sr*LSTR + sc*16 + 8]  = k1;
      *(short8*)&Vts[sr*LSTR + sc*16]     = v0;
      *(short8*)&Vts[sr*LSTR + sc*16 + 8] = v1;
    }
    __syncthreads();
    // S^T = K Q^T per qm: C rows = kj (quad*4+t), cols = q (l15)
    #pragma unroll
    for(int g = 0; g < 4; g++){
      short8 k0 = *(const short8*)&Ks[(g*16 + l15)*LSTR + quad*8];
      short8 k1 = *(const short8*)&Ks[(g*16 + l15)*LSTR + 32 + quad*8];
      #pragma unroll
      for(int qm = 0; qm < 2; qm++){
        f32x4 sa; sa[0]=0.f; sa[1]=0.f; sa[2]=0.f; sa[3]=0.f;
        sa = __builtin_amdgcn_mfma_f32_16x16x32_bf16(k0, qf[qm][0], sa, 0, 0, 0);
        sa = __builtin_amdgcn_mfma_f32_16x16x32_bf16(k1, qf[qm][1], sa, 0, 0, 0);
        float e0 = exp2f(fmaf(sa[0], C1, -C2));
        float e1 = exp2f(fmaf(sa[1], C1, -C2));
        float e2 = exp2f(fmaf(sa[2], C1, -C2));
        float e3 = exp2f(fmaf(sa[3], C1, -C2));
        lsum[qm] += (e0 + e1) + (e2 + e3);
        ushort4 pk;
        pk.x = f2bu_t(e0); pk.y = f2bu_t(e1); pk.z = f2bu_t(e2); pk.w = f2bu_t(e3);
        *(ushort4*)&Ps[w][(qm*16 + l15)*LSTR + g*16 + quad*4] = pk;
      }
    }
    __syncthreads();
    // O += P V  (A = P[q][kj], B = V^T[d][kj])
    short8 a[2][2];
    #pragma unroll
    for(int qm = 0; qm < 2; qm++){
      a[qm][0] = *(const short8*)&Ps[w][(qm*16 + l15)*LSTR + quad*8];
      a[qm][1] = *(const short8*)&Ps[w][(qm*16 + l15)*LSTR + 32 + quad*8];
    }
    #pragma unroll
    for(int g = 0; g < 4; g++){
      short8 b0 = *(const short8*)&Vts[(g*16 + l15)*LSTR + quad*8];
      short8 b1 = *(const short8*)&Vts[(g*16 + l15)*LSTR + 32 + quad*8];
      #pragma unroll
      for(int qm = 0; qm < 2; qm++){
        o_acc[qm][g] = __builtin_amdgcn_mfma_f32_16x16x32_bf16(a[qm][0], b0, o_acc[qm][g], 0, 0, 0);
        o_acc[qm][g] = __builtin_amdgcn_mfma_f32_16x16x32_bf16(a[qm][1], b1, o_acc[qm][g], 0, 0, 0);
      }
    }
  }
  #pragma unroll
  for(int qm = 0; qm < 2; qm++){
    float ls = lsum[qm];
    ls += __shfl_xor(ls, 16);
    ls += __shfl_xor(ls, 32);
    #pragma unroll
    for(int t = 0; t < 4; t++){
      float inv = 1.f / __shfl(ls, quad*4 + t);
      #pragma unroll
      for(int g = 0; g < 4; g++)
        out[(size_t)b*SEQ*DIMN + (size_t)(qb*128 + w*32 + qm*16 + quad*4 + t)*DIMN + h*HDIM + g*16 + l15]
          = f2bu(o_acc[qm][g][t] * inv);
    }
  }
}

// ---------------- block reduce helper ----------------
__device__ __forceinline__ float blockReduceSum(float v, float* red){
  for(int off = 32; off; off >>= 1) v += __shfl_xor(v, off);
  int wid = threadIdx.x >> 6;
  if((threadIdx.x & 63) == 0) red[wid] = v;
  __syncthreads();
  float tot = red[0] + red[1] + red[2] + red[3];
  __syncthreads();
  return tot;
}

// ---------------- xo = justnorm(h + lr*(justnorm(ha) - h)), h = justnorm(x) ----------------
template<typename T1, typename T2, typename TO>
__global__ void k_rn(const T1* __restrict__ x, const T2* __restrict__ ha,
        const float* __restrict__ alpha, TO* __restrict__ xo){
  __shared__ float red[4];
  int row = blockIdx.x, tid = threadIdx.x;
  size_t base = (size_t)row * DIMN;
  float xs[4], hs[4], cs[4];
  float s1 = 0.f, s2 = 0.f;
  for(int j = 0; j < 4; j++){
    int i = tid + j*256;
    float xv = ldv(x + base + i);  xs[j] = xv; s1 += xv*xv;
    float hv = ldv(ha + base + i); hs[j] = hv; s2 += hv*hv;
  }
  s1 = blockReduceSum(s1, red);
  s2 = blockReduceSum(s2, red);
  float r1 = 1.f / fmaxf(sqrtf(s1), 1e-12f);
  float r2 = 1.f / fmaxf(sqrtf(s2), 1e-12f);
  float s3 = 0.f;
  for(int j = 0; j < 4; j++){
    int i = tid + j*256;
    float lr = fabsf(alpha[i] * 1.6f);
    float hn = xs[j] * r1;
    float cv = hn + lr*(hs[j]*r2 - hn);
    cs[j] = cv; s3 += cv*cv;
  }
  s3 = blockReduceSum(s3, red);
  float r3 = 1.f / fmaxf(sqrtf(s3), 1e-12f);
  for(int j = 0; j < 4; j++){
    int i = tid + j*256;
    stv(xo + base + i, cs[j] * r3);
  }
}

extern "C" void kernel_launch(void* const* d_in, const int* in_sizes, int n_in,
                              void* d_out, int out_size, void* d_ws, size_t ws_size,
                              hipStream_t stream){
  const float* x   = (const float*)d_in[0];
  const float* fc  = (const float*)d_in[1];
  const float* fs  = (const float*)d_in[2];
  const float* ada = (const float*)d_in[3];
  const float* wq  = (const float*)d_in[4];
  const float* wk  = (const float*)d_in[5];
  const float* wv  = (const float*)d_in[6];
  const float* wo  = (const float*)d_in[7];
  const float* sqk = (const float*)d_in[8];
  const float* w1  = (const float*)d_in[9];
  const float* w2  = (const float*)d_in[10];
  const float* w3  = (const float*)d_in[11];
  const float* su  = (const float*)d_in[12];
  const float* sv  = (const float*)d_in[13];
  const float* pw  = (const float*)d_in[14];
  const float* pb  = (const float*)d_in[15];
  const float* aal = (const float*)d_in[16];
  const float* mal = (const float*)d_in[17];
  float* out = (float*)d_out;

  const size_t MM = (size_t)DIMN*DIMN;
  const size_t HM = (size_t)HIDDEN*DIMN;
  const size_t F  = (size_t)ROWS*DIMN;
  char* wsb = (char*)d_ws;
  float* t = (float*)wsb;                      // 1024
  ushort_t* Gpk = (ushort_t*)(wsb + 16384);    // 4*8*8192 el
  ushort_t* wqT = Gpk + 262144;                // QKV weights contiguous -> [3072][1024]
  ushort_t* wkT = wqT + MM;
  ushort_t* wvT = wkT + MM;
  ushort_t* woT = wvT + MM;
  ushort_t* w1T = woT + MM;                    // [2816][1024]
  ushort_t* w3T = w1T + HM;
  ushort_t* w2T = w3T + HM;                    // [1024][2816]
  ushort_t* P1  = w2T + HM;                    // xmod -> attnO -> x1
  ushort_t* QKV = P1 + F;                      // [ROWS][3072] interleaved; later Ha/M2/Hm slots
  ushort_t* Ha  = QKV;                         // h_a   [ROWS][1024]
  ushort_t* M2  = QKV + F;                     // xmod2 [ROWS][1024]
  ushort_t* Hm  = QKV + 2*F;                   // h_m   [ROWS][1024]
  ushort_t* a1  = QKV + 3*F;                   // [FCHUNK][HIDDEN]; aliases Vt
  ushort_t* Vt  = a1;                          // [B][NH][64][SEQ]

  dim3 blk(256);

  k_time<<<dim3(1024), dim3(64), 0, stream>>>(ada, pw, pb, t);
  k_gp<<<dim3(4,8), blk, 0, stream>>>(t, Gpk);

  k_wt<<<dim3(32,32), blk, 0, stream>>>(wq, wqT, DIMN, DIMN);
  k_wt<<<dim3(32,32), blk, 0, stream>>>(wk, wkT, DIMN, DIMN);
  k_wt<<<dim3(32,32), blk, 0, stream>>>(wv, wvT, DIMN, DIMN);
  k_wt<<<dim3(32,32), blk, 0, stream>>>(wo, woT, DIMN, DIMN);
  k_wt<<<dim3(HIDDEN/32,32), blk, 0, stream>>>(w1, w1T, DIMN, HIDDEN);
  k_wt<<<dim3(HIDDEN/32,32), blk, 0, stream>>>(w3, w3T, DIMN, HIDDEN);
  k_wt<<<dim3(32,HIDDEN/32), blk, 0, stream>>>(w2, w2T, HIDDEN, DIMN);

  // attention branch
  k_modmf<float><<<dim3(2,128,BATCH), blk, 0, stream>>>(x, Gpk, P1);
  k_gemm_mf<128,128,ushort_t><<<dim3(24,32), blk, 0, stream>>>(P1, wqT, QKV, QKVS, DIMN);
  k_qkvprep<<<dim3(NHEAD/4,SEQ,BATCH), blk, 0, stream>>>(QKV, fc, fs, sqk);
  k_vt<<<dim3(SEQ/64,NHEAD,BATCH), blk, 0, stream>>>(QKV, Vt);
  k_flash_mf<<<dim3(SEQ/128,NHEAD,BATCH), blk, 0, stream>>>(QKV, Vt, P1);
  k_gemm_mf<128,128,ushort_t><<<dim3(8,32), blk, 0, stream>>>(P1, woT, Ha, DIMN, DIMN);
  k_rn<float,ushort_t,ushort_t><<<dim3(ROWS), blk, 0, stream>>>(x, Ha, aal, P1);

  // FFN branch
  k_modmf<ushort_t><<<dim3(2,128,BATCH), blk, 0, stream>>>(P1, Gpk + 131072, M2);
  for(int c2 = 0; c2 < ROWS/FCHUNK; c2++){
    const ushort_t* Ac = M2 + (size_t)c2*FCHUNK*DIMN;
    k_ffn12<<<dim3(HIDDEN/64,FCHUNK/128), blk, 0, stream>>>(Ac, w1T, w3T, su, sv, a1, DIMN);
    k_gemm_mf<128,128,ushort_t><<<dim3(8,FCHUNK/128), blk, 0, stream>>>(a1, w2T, Hm + (size_t)c2*FCHUNK*DIMN, DIMN, HIDDEN);
  }

  k_rn<ushort_t,ushort_t,float><<<dim3(ROWS), blk, 0, stream>>>(P1, Hm, mal, out);
}

// Round 8
// 512.385 us; speedup vs baseline: 1.1290x; 1.1290x over previous
//
#include <hip/hip_runtime.h>
#include <hip/hip_bf16.h>
#include <math.h>

#define SEQ    2048
#define DIMN   1024
#define NHEAD  16
#define HDIM   64
#define BATCH  2
#define ROWS   4096
#define HIDDEN 2816
#define FCHUNK 2048
#define QKVS   3072       // interleaved QKV row stride

typedef __attribute__((ext_vector_type(8))) short short8;
typedef __attribute__((ext_vector_type(4))) float f32x4;
typedef unsigned short ushort_t;
typedef __attribute__((address_space(1))) void gas_t;
typedef __attribute__((address_space(3))) void las_t;

__device__ __forceinline__ float bfbits(ushort_t u){ return __uint_as_float(((unsigned)u) << 16); }
__device__ __forceinline__ ushort_t f2bu(float f){
  __hip_bfloat16 h = __float2bfloat16(f);
  return *reinterpret_cast<ushort_t*>(&h);
}
__device__ __forceinline__ ushort_t f2bu_t(float f){ return (ushort_t)(__float_as_uint(f) >> 16); }
__device__ __forceinline__ float ldv(const float* p){ return *p; }
__device__ __forceinline__ float ldv(const ushort_t* p){ return bfbits(*p); }
__device__ __forceinline__ void stv(float* p, float v){ *p = v; }
__device__ __forceinline__ void stv(ushort_t* p, float v){ *p = f2bu(v); }
__device__ __forceinline__ void async_cp16(const ushort_t* g, ushort_t* l){
  __builtin_amdgcn_global_load_lds((gas_t*)g, (las_t*)l, 16, 0, 0);
}
__device__ __forceinline__ ushort4 ld4u(const float* p){
  float4 v = *(const float4*)p;
  ushort4 u; u.x = f2bu(v.x); u.y = f2bu(v.y); u.z = f2bu(v.z); u.w = f2bu(v.w);
  return u;
}
__device__ __forceinline__ ushort4 ld4u(const ushort_t* p){ return *(const ushort4*)p; }

// ---------------- t = silu(adafm_input) @ proj_w + proj_b ----------------
__global__ void k_time(const float* __restrict__ ada, const float* __restrict__ pw,
                       const float* __restrict__ pb, float* __restrict__ t){
  int b = blockIdx.x >> 9, o = blockIdx.x & 511, lane = threadIdx.x;
  float acc = 0.f;
  for(int i = lane; i < DIMN; i += 64){
    float a = ada[b*DIMN + i];
    float s = a / (1.f + expf(-a));
    acc += s * pw[i*512 + o];
  }
  for(int off = 32; off; off >>= 1) acc += __shfl_down(acc, off);
  if(lane == 0) t[b*512 + o] = acc + pb[o];
}

// ---------------- fused: g_wb[n] then circulant pack Gpk[wb][kc][n][mm] ----------------
__global__ void k_gp(const float* __restrict__ t, ushort_t* __restrict__ Gpk){
  __shared__ float gl[256];
  int wb = blockIdx.x, kc = blockIdx.y, tid = threadIdx.x;
  int b = wb & 1, which = wb >> 1;
  const float C = 6.283185307179586f / 256.f;
  float acc = 0.f;
  for(int k = 0; k < 256; k++){
    float f = t[b*512 + which*256 + k];
    acc += f * cosf(C * (float)((k*tid) & 255));
  }
  gl[tid] = acc * (1.f/256.f);
  __syncthreads();
  ushort_t* ob = Gpk + ((size_t)(wb*8 + kc))*8192;
  for(int rep = 0; rep < 4; rep++){
    int n = rep*64 + (tid >> 2), mmb = (tid & 3)*8;
    short8 o;
    #pragma unroll
    for(int j = 0; j < 8; j++)
      o[j] = (short)f2bu(gl[(n - kc*32 - (mmb + j)) & 255]);
    *(short8*)(ob + n*32 + mmb) = o;
  }
}

// ---------------- MFMA modulate: per-patch circular conv as GEMM ----------------
#define APAD 264
#define GPAD 40
template<typename IN>
__global__ __launch_bounds__(256) void k_modmf(const IN* __restrict__ src,
        const ushort_t* __restrict__ Gpk, ushort_t* __restrict__ dst){
  __shared__ __align__(16) ushort_t Ap[64*APAD];
  __shared__ __align__(16) ushort_t Gs[128*GPAD];
  int nh = blockIdx.x, i = blockIdx.y, b = blockIdx.z;
  int tid = threadIdx.x, lane = tid & 63, w = tid >> 6;
  int l15 = lane & 15, quad = lane >> 4;
  const IN* xb = src + (size_t)b*SEQ*DIMN + (size_t)(i*16)*DIMN;
  int j = tid >> 2, c = (tid & 3)*4;
  #pragma unroll 4
  for(int rep = 0; rep < 16; rep++){
    ushort4 v4 = ld4u(xb + (size_t)rep*DIMN + tid*4);
    *(ushort4*)&Ap[j*APAD + rep*16 + c] = v4;
  }
  f32x4 acc[8];
  #pragma unroll
  for(int nt = 0; nt < 8; nt++){ acc[nt][0]=0.f; acc[nt][1]=0.f; acc[nt][2]=0.f; acc[nt][3]=0.f; }
  for(int kc = 0; kc < 8; kc++){
    __syncthreads();
    {
      const ushort_t* gsrc = Gpk + ((size_t)(b*8 + kc))*8192 + nh*4096;
      #pragma unroll
      for(int r2 = 0; r2 < 2; r2++){
        int n = r2*64 + (tid >> 2), mm = (tid & 3)*8;
        *(short8*)&Gs[n*GPAD + mm] = *(const short8*)(gsrc + r2*2048 + tid*8);
      }
    }
    __syncthreads();
    short8 af = *(const short8*)&Ap[(w*16 + l15)*APAD + kc*32 + quad*8];
    #pragma unroll
    for(int nt = 0; nt < 8; nt++){
      short8 bf = *(const short8*)&Gs[(nt*16 + l15)*GPAD + quad*8];
      acc[nt] = __builtin_amdgcn_mfma_f32_16x16x32_bf16(af, bf, acc[nt], 0, 0, 0);
    }
  }
  size_t ob = (size_t)b*SEQ*DIMN + (size_t)(i*16 + nh*8)*DIMN + (w*16 + quad*4)*16 + l15;
  #pragma unroll
  for(int nt = 0; nt < 8; nt++)
    #pragma unroll
    for(int t = 0; t < 4; t++)
      dst[ob + (size_t)nt*DIMN + t*16] = f2bu(acc[nt][t]);
}

// ---------------- weight transpose: fp32 W[K][N] -> bf16 Wt[N][K] ----------------
__global__ void k_wt(const float* __restrict__ W, ushort_t* __restrict__ Wt, int K, int N){
  __shared__ float tile[32][33];
  int k0 = blockIdx.y*32, n0 = blockIdx.x*32;
  int r = threadIdx.x >> 3, c4 = (threadIdx.x & 7)*4;
  float4 v = *(const float4*)(W + (size_t)(k0 + r)*N + n0 + c4);
  tile[r][c4+0] = v.x; tile[r][c4+1] = v.y; tile[r][c4+2] = v.z; tile[r][c4+3] = v.w;
  __syncthreads();
  ushort4 o;
  o.x = f2bu(tile[c4+0][r]); o.y = f2bu(tile[c4+1][r]);
  o.z = f2bu(tile[c4+2][r]); o.w = f2bu(tile[c4+3][r]);
  *(ushort4*)(Wt + (size_t)(n0 + r)*K + k0 + c4) = o;
}

// ---------------- m97-style MFMA GEMM: C(MxN) = A(MxK) @ Wt(NxK)^T ----------------
template<int BM, int BN, typename OUT>
__global__ __launch_bounds__(256) void k_gemm_mf(const ushort_t* __restrict__ A,
        const ushort_t* __restrict__ Wt, OUT* __restrict__ C, int N, int K){
  constexpr int MT = BM/32, NT = BN/32;
  constexpr int AI = BM/64, BI = BN/64;
  __shared__ __align__(16) ushort_t As[BM*32];
  __shared__ __align__(16) ushort_t Bs[BN*32];
  int tid = threadIdx.x, lane = tid & 63, w = tid >> 6;
  int l15 = lane & 15, quad = lane >> 4;
  int m0 = blockIdx.y*BM, n0 = blockIdx.x*BN;
  int wr = (w>>1)*(BM/2), wc = (w&1)*(BN/2);
  int srow = lane >> 2, scol = (lane & 3)*8;
  const ushort_t* ag[AI]; ushort_t* al[AI];
  const ushort_t* bg[BI]; ushort_t* bl[BI];
  #pragma unroll
  for(int i = 0; i < AI; i++){
    int rb = w*AI + i;
    ag[i] = A + (size_t)(m0 + rb*16 + srow)*K + scol;
    al[i] = As + rb*512 + lane*8;
  }
  #pragma unroll
  for(int i = 0; i < BI; i++){
    int rb = w*BI + i;
    bg[i] = Wt + (size_t)(n0 + rb*16 + srow)*K + scol;
    bl[i] = Bs + rb*512 + lane*8;
  }
  f32x4 acc[MT][NT];
  #pragma unroll
  for(int mt = 0; mt < MT; mt++)
    #pragma unroll
    for(int nt = 0; nt < NT; nt++)
      for(int t = 0; t < 4; t++) acc[mt][nt][t] = 0.f;
  for(int kk = 0; kk < K; kk += 32){
    __syncthreads();
    #pragma unroll
    for(int i = 0; i < AI; i++) async_cp16(ag[i] + kk, al[i]);
    #pragma unroll
    for(int i = 0; i < BI; i++) async_cp16(bg[i] + kk, bl[i]);
    __syncthreads();
    short8 af[MT], bf[NT];
    #pragma unroll
    for(int mt = 0; mt < MT; mt++) af[mt] = *(const short8*)&As[(wr + mt*16 + l15)*32 + quad*8];
    #pragma unroll
    for(int nt = 0; nt < NT; nt++) bf[nt] = *(const short8*)&Bs[(wc + nt*16 + l15)*32 + quad*8];
    #pragma unroll
    for(int mt = 0; mt < MT; mt++)
      #pragma unroll
      for(int nt = 0; nt < NT; nt++)
        acc[mt][nt] = __builtin_amdgcn_mfma_f32_16x16x32_bf16(af[mt], bf[nt], acc[mt][nt], 0, 0, 0);
  }
  #pragma unroll
  for(int mt = 0; mt < MT; mt++)
    #pragma unroll
    for(int nt = 0; nt < NT; nt++)
      #pragma unroll
      for(int t = 0; t < 4; t++)
        stv(C + (size_t)(m0 + wr + mt*16 + quad*4 + t)*N + n0 + wc + nt*16 + l15, acc[mt][nt][t]);
}

// ---------------- fused FFN up: h = silu(A@w1 * sv*sqrt(H)) * (A@w3 * su) ----------------
__global__ __launch_bounds__(256) void k_ffn12(const ushort_t* __restrict__ A,
        const ushort_t* __restrict__ W1t, const ushort_t* __restrict__ W3t,
        const float* __restrict__ su, const float* __restrict__ sv,
        ushort_t* __restrict__ H, int K){
  __shared__ __align__(16) ushort_t As[128*32];
  __shared__ __align__(16) ushort_t B1s[64*32];
  __shared__ __align__(16) ushort_t B3s[64*32];
  int tid = threadIdx.x, lane = tid & 63, w = tid >> 6;
  int l15 = lane & 15, quad = lane >> 4;
  int m0 = blockIdx.y*128, n0 = blockIdx.x*64;
  int wr = (w>>1)*64, wc = (w&1)*32;
  int srow = lane >> 2, scol = (lane & 3)*8;
  const ushort_t* ag[2]; ushort_t* al[2];
  #pragma unroll
  for(int i = 0; i < 2; i++){
    int rb = w*2 + i;
    ag[i] = A + (size_t)(m0 + rb*16 + srow)*K + scol;
    al[i] = As + rb*512 + lane*8;
  }
  const ushort_t* b1g = W1t + (size_t)(n0 + w*16 + srow)*K + scol;
  const ushort_t* b3g = W3t + (size_t)(n0 + w*16 + srow)*K + scol;
  ushort_t* b1l = B1s + w*512 + lane*8;
  ushort_t* b3l = B3s + w*512 + lane*8;
  f32x4 acc1[4][2], acc3[4][2];
  #pragma unroll
  for(int mt = 0; mt < 4; mt++)
    #pragma unroll
    for(int nt = 0; nt < 2; nt++)
      for(int t = 0; t < 4; t++){ acc1[mt][nt][t] = 0.f; acc3[mt][nt][t] = 0.f; }
  for(int kk = 0; kk < K; kk += 32){
    __syncthreads();
    async_cp16(ag[0] + kk, al[0]);
    async_cp16(ag[1] + kk, al[1]);
    async_cp16(b1g + kk, b1l);
    async_cp16(b3g + kk, b3l);
    __syncthreads();
    short8 af[4], b1f[2], b3f[2];
    #pragma unroll
    for(int mt = 0; mt < 4; mt++) af[mt] = *(const short8*)&As[(wr + mt*16 + l15)*32 + quad*8];
    #pragma unroll
    for(int nt = 0; nt < 2; nt++){
      b1f[nt] = *(const short8*)&B1s[(wc + nt*16 + l15)*32 + quad*8];
      b3f[nt] = *(const short8*)&B3s[(wc + nt*16 + l15)*32 + quad*8];
    }
    #pragma unroll
    for(int mt = 0; mt < 4; mt++)
      #pragma unroll
      for(int nt = 0; nt < 2; nt++){
        acc1[mt][nt] = __builtin_amdgcn_mfma_f32_16x16x32_bf16(af[mt], b1f[nt], acc1[mt][nt], 0, 0, 0);
        acc3[mt][nt] = __builtin_amdgcn_mfma_f32_16x16x32_bf16(af[mt], b3f[nt], acc3[mt][nt], 0, 0, 0);
      }
  }
  #pragma unroll
  for(int nt = 0; nt < 2; nt++){
    int n = n0 + wc + nt*16 + l15;
    float svv = sv[n] * 53.06599665f, suv = su[n];
    #pragma unroll
    for(int mt = 0; mt < 4; mt++)
      #pragma unroll
      for(int t = 0; t < 4; t++){
        float hpre = acc1[mt][nt][t] * svv;
        float sil = hpre / (1.f + expf(-hpre));
        float hv = sil * (acc3[mt][nt][t] * suv);
        H[(size_t)(m0 + wr + mt*16 + quad*4 + t)*HIDDEN + n] = f2bu(hv);
      }
  }
}

// ---------------- rotary + justnorm + sqk scale, in place on interleaved QKV ----------------
__global__ void k_qkvprep(ushort_t* __restrict__ qkv, const float* __restrict__ fc,
        const float* __restrict__ fs, const float* __restrict__ sqk){
  int w = threadIdx.x >> 6, d = threadIdx.x & 63;
  int h = blockIdx.x*4 + w, s = blockIdx.y, b = blockIdx.z;
  size_t ib = ((size_t)(b*SEQ + s))*QKVS + h*HDIM + d;
  float q = bfbits(qkv[ib]), k = bfbits(qkv[ib + 1024]);
  float qn = __shfl_xor(q, 1), kn = __shfl_xor(k, 1);
  int p = d >> 1;
  float c = fc[s*32 + p], sn = fs[s*32 + p];
  float qr, kr;
  if((d & 1) == 0){ qr = q*c - qn*sn; kr = k*c - kn*sn; }
  else            { qr = qn*sn + q*c; kr = kn*sn + k*c; }
  float sq = qr*qr, sk = kr*kr;
  for(int off = 32; off; off >>= 1){ sq += __shfl_xor(sq, off); sk += __shfl_xor(sk, off); }
  float scl = sqk[h*HDIM + d] * 32.f;
  qkv[ib]        = f2bu(scl * qr / fmaxf(sqrtf(sq), 1e-12f));
  qkv[ib + 1024] = f2bu(scl * kr / fmaxf(sqrtf(sk), 1e-12f));
}

// ---------------- V transpose (from interleaved QKV) to [b][h][d][s] ----------------
__global__ void k_vt(const ushort_t* __restrict__ qkv, ushort_t* __restrict__ vto){
  __shared__ ushort_t tile[64][72];
  int s0 = blockIdx.x*64, h = blockIdx.y, b = blockIdx.z;
  int r = threadIdx.x >> 2, c = (threadIdx.x & 3)*16;
  const ushort_t* src = qkv + (size_t)(b*SEQ + s0 + r)*QKVS + 2048 + h*HDIM + c;
  *(short8*)&tile[r][c]     = *(const short8*)src;
  *(short8*)&tile[r][c + 8] = *(const short8*)(src + 8);
  __syncthreads();
  ushort_t* dst = vto + ((size_t)(b*NHEAD + h)*HDIM + r)*SEQ + s0 + c;
  for(int j = 0; j < 16; j += 4){
    ushort4 o;
    o.x = tile[c+j][r]; o.y = tile[c+j+1][r]; o.z = tile[c+j+2][r]; o.w = tile[c+j+3][r];
    *(ushort4*)(dst + j) = o;
  }
}

// ---------------- MFMA flash attention: 64 q-rows/block, fixed-max softmax, reg prefetch ----------------
// grid (SEQ/64, NH, B), 4 waves. Next chunk's K/V loaded into registers during compute.
#define LSTR 72
__global__ __launch_bounds__(256) void k_flash_mf(const ushort_t* __restrict__ qkv,
        const ushort_t* __restrict__ vt, ushort_t* __restrict__ out){
  int qb = blockIdx.x, h = blockIdx.y, b = blockIdx.z;
  int tid = threadIdx.x, lane = tid & 63, w = tid >> 6;
  int l15 = lane & 15, quad = lane >> 4;
  __shared__ __align__(16) ushort_t Ks[64*LSTR], Vts[64*LSTR];
  __shared__ __align__(16) ushort_t Ps[4][16*LSTR];
  size_t qkb = (size_t)b*SEQ*QKVS + h*HDIM;
  size_t ob  = (size_t)b*SEQ*DIMN + h*HDIM;
  const ushort_t* vb = vt + (size_t)(b*NHEAD + h)*HDIM*SEQ;
  short8 qf0, qf1;
  {
    const ushort_t* qrow = qkv + qkb + (size_t)(qb*64 + w*16 + l15)*QKVS;
    qf0 = *(const short8*)(qrow + quad*8);
    qf1 = *(const short8*)(qrow + 32 + quad*8);
  }
  f32x4 o_acc[4];
  #pragma unroll
  for(int g = 0; g < 4; g++){ o_acc[g][0]=0.f; o_acc[g][1]=0.f; o_acc[g][2]=0.f; o_acc[g][3]=0.f; }
  float lsum = 0.f;
  int sr = tid >> 2, sc = tid & 3;
  const ushort_t* kbase = qkv + qkb + 1024 + (size_t)sr*QKVS + sc*16;
  const ushort_t* vbase = vb + (size_t)sr*SEQ + sc*16;
  // prefetch chunk 0 into registers
  short8 kr0 = *(const short8*)kbase,       kr1 = *(const short8*)(kbase + 8);
  short8 vr0 = *(const short8*)vbase,       vr1 = *(const short8*)(vbase + 8);
  const float C1 = 11.54156036f;   // 8*log2(e)
  const float C2 = 11.90223409f;   // 8.25*log2(e): scores provably < 8.04
  for(int ch = 0; ch < SEQ/64; ch++){
    __syncthreads();                       // previous compute done reading LDS
    *(short8*)&Ks[sr*LSTR + sc*16]      = kr0;
    *(short8*)&Ks[sr*LSTR + sc*16 + 8]  = kr1;
    *(short8*)&Vts[sr*LSTR + sc*16]     = vr0;
    *(short8*)&Vts[sr*LSTR + sc*16 + 8] = vr1;
    if(ch + 1 < SEQ/64){                   // issue next chunk's loads; complete during compute
      const ushort_t* kn = kbase + (size_t)(ch + 1)*64*QKVS;
      const ushort_t* vn = vbase + (ch + 1)*64;
      kr0 = *(const short8*)kn; kr1 = *(const short8*)(kn + 8);
      vr0 = *(const short8*)vn; vr1 = *(const short8*)(vn + 8);
    }
    __syncthreads();
    // S^T = K Q^T : C rows = kj, cols = q
    #pragma unroll
    for(int g = 0; g < 4; g++){
      f32x4 sa; sa[0]=0.f; sa[1]=0.f; sa[2]=0.f; sa[3]=0.f;
      short8 k0 = *(const short8*)&Ks[(g*16 + l15)*LSTR + quad*8];
      short8 k1 = *(const short8*)&Ks[(g*16 + l15)*LSTR + 32 + quad*8];
      sa = __builtin_amdgcn_mfma_f32_16x16x32_bf16(k0, qf0, sa, 0, 0, 0);
      sa = __builtin_amdgcn_mfma_f32_16x16x32_bf16(k1, qf1, sa, 0, 0, 0);
      float e0 = exp2f(fmaf(sa[0], C1, -C2));
      float e1 = exp2f(fmaf(sa[1], C1, -C2));
      float e2 = exp2f(fmaf(sa[2], C1, -C2));
      float e3 = exp2f(fmaf(sa[3], C1, -C2));
      lsum += (e0 + e1) + (e2 + e3);
      ushort4 pk;
      pk.x = f2bu_t(e0); pk.y = f2bu_t(e1); pk.z = f2bu_t(e2); pk.w = f2bu_t(e3);
      *(ushort4*)&Ps[w][l15*LSTR + g*16 + quad*4] = pk;   // wave-private: no barrier needed
    }
    short8 a0 = *(const short8*)&Ps[w][l15*LSTR + quad*8];
    short8 a1 = *(const short8*)&Ps[w][l15*LSTR + 32 + quad*8];
    #pragma unroll
    for(int g = 0; g < 4; g++){
      short8 b0 = *(const short8*)&Vts[(g*16 + l15)*LSTR + quad*8];
      short8 b1 = *(const short8*)&Vts[(g*16 + l15)*LSTR + 32 + quad*8];
      o_acc[g] = __builtin_amdgcn_mfma_f32_16x16x32_bf16(a0, b0, o_acc[g], 0, 0, 0);
      o_acc[g] = __builtin_amdgcn_mfma_f32_16x16x32_bf16(a1, b1, o_acc[g], 0, 0, 0);
    }
  }
  lsum += __shfl_xor(lsum, 16);
  lsum += __shfl_xor(lsum, 32);
  #pragma unroll
  for(int t = 0; t < 4; t++){
    float inv = 1.f / __shfl(lsum, quad*4 + t);
    #pragma unroll
    for(int g = 0; g < 4; g++)
      out[ob + (size_t)(qb*64 + w*16 + quad*4 + t)*DIMN + g*16 + l15] = f2bu(o_acc[g][t] * inv);
  }
}

// ---------------- block reduce helper ----------------
__device__ __forceinline__ float blockReduceSum(float v, float* red){
  for(int off = 32; off; off >>= 1) v += __shfl_xor(v, off);
  int wid = threadIdx.x >> 6;
  if((threadIdx.x & 63) == 0) red[wid] = v;
  __syncthreads();
  float tot = red[0] + red[1] + red[2] + red[3];
  __syncthreads();
  return tot;
}

// ---------------- xo = justnorm(h + lr*(justnorm(ha) - h)), h = justnorm(x) ----------------
template<typename T1, typename T2, typename TO>
__global__ void k_rn(const T1* __restrict__ x, const T2* __restrict__ ha,
        const float* __restrict__ alpha, TO* __restrict__ xo){
  __shared__ float red[4];
  int row = blockIdx.x, tid = threadIdx.x;
  size_t base = (size_t)row * DIMN;
  float xs[4], hs[4], cs[4];
  float s1 = 0.f, s2 = 0.f;
  for(int j = 0; j < 4; j++){
    int i = tid + j*256;
    float xv = ldv(x + base + i);  xs[j] = xv; s1 += xv*xv;
    float hv = ldv(ha + base + i); hs[j] = hv; s2 += hv*hv;
  }
  s1 = blockReduceSum(s1, red);
  s2 = blockReduceSum(s2, red);
  float r1 = 1.f / fmaxf(sqrtf(s1), 1e-12f);
  float r2 = 1.f / fmaxf(sqrtf(s2), 1e-12f);
  float s3 = 0.f;
  for(int j = 0; j < 4; j++){
    int i = tid + j*256;
    float lr = fabsf(alpha[i] * 1.6f);
    float hn = xs[j] * r1;
    float cv = hn + lr*(hs[j]*r2 - hn);
    cs[j] = cv; s3 += cv*cv;
  }
  s3 = blockReduceSum(s3, red);
  float r3 = 1.f / fmaxf(sqrtf(s3), 1e-12f);
  for(int j = 0; j < 4; j++){
    int i = tid + j*256;
    stv(xo + base + i, cs[j] * r3);
  }
}

extern "C" void kernel_launch(void* const* d_in, const int* in_sizes, int n_in,
                              void* d_out, int out_size, void* d_ws, size_t ws_size,
                              hipStream_t stream){
  const float* x   = (const float*)d_in[0];
  const float* fc  = (const float*)d_in[1];
  const float* fs  = (const float*)d_in[2];
  const float* ada = (const float*)d_in[3];
  const float* wq  = (const float*)d_in[4];
  const float* wk  = (const float*)d_in[5];
  const float* wv  = (const float*)d_in[6];
  const float* wo  = (const float*)d_in[7];
  const float* sqk = (const float*)d_in[8];
  const float* w1  = (const float*)d_in[9];
  const float* w2  = (const float*)d_in[10];
  const float* w3  = (const float*)d_in[11];
  const float* su  = (const float*)d_in[12];
  const float* sv  = (const float*)d_in[13];
  const float* pw  = (const float*)d_in[14];
  const float* pb  = (const float*)d_in[15];
  const float* aal = (const float*)d_in[16];
  const float* mal = (const float*)d_in[17];
  float* out = (float*)d_out;

  const size_t MM = (size_t)DIMN*DIMN;
  const size_t HM = (size_t)HIDDEN*DIMN;
  const size_t F  = (size_t)ROWS*DIMN;
  char* wsb = (char*)d_ws;
  float* t = (float*)wsb;                      // 1024
  ushort_t* Gpk = (ushort_t*)(wsb + 16384);    // 4*8*8192 el
  ushort_t* wqT = Gpk + 262144;                // QKV weights contiguous -> [3072][1024]
  ushort_t* wkT = wqT + MM;
  ushort_t* wvT = wkT + MM;
  ushort_t* woT = wvT + MM;
  ushort_t* w1T = woT + MM;                    // [2816][1024]
  ushort_t* w3T = w1T + HM;
  ushort_t* w2T = w3T + HM;                    // [1024][2816]
  ushort_t* P1  = w2T + HM;                    // xmod -> attnO -> x1
  ushort_t* QKV = P1 + F;                      // [ROWS][3072]; later Ha/M2/Hm slots
  ushort_t* Ha  = QKV;                         // h_a   [ROWS][1024]
  ushort_t* M2  = QKV + F;                     // xmod2 [ROWS][1024]
  ushort_t* Hm  = QKV + 2*F;                   // h_m   [ROWS][1024]
  ushort_t* a1  = QKV + 3*F;                   // [FCHUNK][HIDDEN]; aliases Vt
  ushort_t* Vt  = a1;                          // [B][NH][64][SEQ]

  dim3 blk(256);

  k_time<<<dim3(1024), dim3(64), 0, stream>>>(ada, pw, pb, t);
  k_gp<<<dim3(4,8), blk, 0, stream>>>(t, Gpk);

  k_wt<<<dim3(32,32), blk, 0, stream>>>(wq, wqT, DIMN, DIMN);
  k_wt<<<dim3(32,32), blk, 0, stream>>>(wk, wkT, DIMN, DIMN);
  k_wt<<<dim3(32,32), blk, 0, stream>>>(wv, wvT, DIMN, DIMN);
  k_wt<<<dim3(32,32), blk, 0, stream>>>(wo, woT, DIMN, DIMN);
  k_wt<<<dim3(HIDDEN/32,32), blk, 0, stream>>>(w1, w1T, DIMN, HIDDEN);
  k_wt<<<dim3(HIDDEN/32,32), blk, 0, stream>>>(w3, w3T, DIMN, HIDDEN);
  k_wt<<<dim3(32,HIDDEN/32), blk, 0, stream>>>(w2, w2T, HIDDEN, DIMN);

  // attention branch
  k_modmf<float><<<dim3(2,128,BATCH), blk, 0, stream>>>(x, Gpk, P1);
  k_gemm_mf<128,128,ushort_t><<<dim3(24,32), blk, 0, stream>>>(P1, wqT, QKV, QKVS, DIMN);
  k_qkvprep<<<dim3(NHEAD/4,SEQ,BATCH), blk, 0, stream>>>(QKV, fc, fs, sqk);
  k_vt<<<dim3(SEQ/64,NHEAD,BATCH), blk, 0, stream>>>(QKV, Vt);
  k_flash_mf<<<dim3(SEQ/64,NHEAD,BATCH), blk, 0, stream>>>(QKV, Vt, P1);
  k_gemm_mf<128,64,ushort_t><<<dim3(16,32), blk, 0, stream>>>(P1, woT, Ha, DIMN, DIMN);
  k_rn<float,ushort_t,ushort_t><<<dim3(ROWS), blk, 0, stream>>>(x, Ha, aal, P1);

  // FFN branch
  k_modmf<ushort_t><<<dim3(2,128,BATCH), blk, 0, stream>>>(P1, Gpk + 131072, M2);
  for(int c2 = 0; c2 < ROWS/FCHUNK; c2++){
    const ushort_t* Ac = M2 + (size_t)c2*FCHUNK*DIMN;
    k_ffn12<<<dim3(HIDDEN/64,FCHUNK/128), blk, 0, stream>>>(Ac, w1T, w3T, su, sv, a1, DIMN);
    k_gemm_mf<64,64,ushort_t><<<dim3(16,FCHUNK/64), blk, 0, stream>>>(a1, w2T, Hm + (size_t)c2*FCHUNK*DIMN, DIMN, HIDDEN);
  }

  k_rn<ushort_t,ushort_t,float><<<dim3(ROWS), blk, 0, stream>>>(P1, Hm, mal, out);
}

// Round 9
// 495.684 us; speedup vs baseline: 1.1670x; 1.0337x over previous
//
#include <hip/hip_runtime.h>
#include <hip/hip_bf16.h>
#include <math.h>

#define SEQ    2048
#define DIMN   1024
#define NHEAD  16
#define HDIM   64
#define BATCH  2
#define ROWS   4096
#define HIDDEN 2816
#define QKVS   3072       // interleaved QKV row stride

typedef __attribute__((ext_vector_type(8))) short short8;
typedef __attribute__((ext_vector_type(4))) float f32x4;
typedef unsigned short ushort_t;
typedef __attribute__((address_space(1))) void gas_t;
typedef __attribute__((address_space(3))) void las_t;

__device__ __forceinline__ float bfbits(ushort_t u){ return __uint_as_float(((unsigned)u) << 16); }
__device__ __forceinline__ ushort_t f2bu(float f){
  __hip_bfloat16 h = __float2bfloat16(f);
  return *reinterpret_cast<ushort_t*>(&h);
}
__device__ __forceinline__ ushort_t f2bu_t(float f){ return (ushort_t)(__float_as_uint(f) >> 16); }
__device__ __forceinline__ float ldv(const float* p){ return *p; }
__device__ __forceinline__ float ldv(const ushort_t* p){ return bfbits(*p); }
__device__ __forceinline__ void stv(float* p, float v){ *p = v; }
__device__ __forceinline__ void stv(ushort_t* p, float v){ *p = f2bu(v); }
__device__ __forceinline__ void async_cp16(const ushort_t* g, ushort_t* l){
  __builtin_amdgcn_global_load_lds((gas_t*)g, (las_t*)l, 16, 0, 0);
}
__device__ __forceinline__ ushort4 ld4u(const float* p){
  float4 v = *(const float4*)p;
  ushort4 u; u.x = f2bu(v.x); u.y = f2bu(v.y); u.z = f2bu(v.z); u.w = f2bu(v.w);
  return u;
}
__device__ __forceinline__ ushort4 ld4u(const ushort_t* p){ return *(const ushort4*)p; }

// ---------------- t = silu(adafm_input) @ proj_w + proj_b ----------------
__global__ void k_time(const float* __restrict__ ada, const float* __restrict__ pw,
                       const float* __restrict__ pb, float* __restrict__ t){
  int b = blockIdx.x >> 9, o = blockIdx.x & 511, lane = threadIdx.x;
  float acc = 0.f;
  for(int i = lane; i < DIMN; i += 64){
    float a = ada[b*DIMN + i];
    float s = a / (1.f + expf(-a));
    acc += s * pw[i*512 + o];
  }
  for(int off = 32; off; off >>= 1) acc += __shfl_down(acc, off);
  if(lane == 0) t[b*512 + o] = acc + pb[o];
}

// ---------------- fused: g_wb[n] then circulant pack Gpk[wb][kc][n][mm] ----------------
__global__ void k_gp(const float* __restrict__ t, ushort_t* __restrict__ Gpk){
  __shared__ float gl[256];
  int wb = blockIdx.x, kc = blockIdx.y, tid = threadIdx.x;
  int b = wb & 1, which = wb >> 1;
  const float C = 6.283185307179586f / 256.f;
  float acc = 0.f;
  for(int k = 0; k < 256; k++){
    float f = t[b*512 + which*256 + k];
    acc += f * cosf(C * (float)((k*tid) & 255));
  }
  gl[tid] = acc * (1.f/256.f);
  __syncthreads();
  ushort_t* ob = Gpk + ((size_t)(wb*8 + kc))*8192;
  for(int rep = 0; rep < 4; rep++){
    int n = rep*64 + (tid >> 2), mmb = (tid & 3)*8;
    short8 o;
    #pragma unroll
    for(int j = 0; j < 8; j++)
      o[j] = (short)f2bu(gl[(n - kc*32 - (mmb + j)) & 255]);
    *(short8*)(ob + n*32 + mmb) = o;
  }
}

// ---------------- MFMA modulate: per-patch circular conv as GEMM ----------------
#define APAD 264
#define GPAD 40
template<typename IN>
__global__ __launch_bounds__(256) void k_modmf(const IN* __restrict__ src,
        const ushort_t* __restrict__ Gpk, ushort_t* __restrict__ dst){
  __shared__ __align__(16) ushort_t Ap[64*APAD];
  __shared__ __align__(16) ushort_t Gs[128*GPAD];
  int nh = blockIdx.x, i = blockIdx.y, b = blockIdx.z;
  int tid = threadIdx.x, lane = tid & 63, w = tid >> 6;
  int l15 = lane & 15, quad = lane >> 4;
  const IN* xb = src + (size_t)b*SEQ*DIMN + (size_t)(i*16)*DIMN;
  int j = tid >> 2, c = (tid & 3)*4;
  #pragma unroll 4
  for(int rep = 0; rep < 16; rep++){
    ushort4 v4 = ld4u(xb + (size_t)rep*DIMN + tid*4);
    *(ushort4*)&Ap[j*APAD + rep*16 + c] = v4;
  }
  f32x4 acc[8];
  #pragma unroll
  for(int nt = 0; nt < 8; nt++){ acc[nt][0]=0.f; acc[nt][1]=0.f; acc[nt][2]=0.f; acc[nt][3]=0.f; }
  for(int kc = 0; kc < 8; kc++){
    __syncthreads();
    {
      const ushort_t* gsrc = Gpk + ((size_t)(b*8 + kc))*8192 + nh*4096;
      #pragma unroll
      for(int r2 = 0; r2 < 2; r2++){
        int n = r2*64 + (tid >> 2), mm = (tid & 3)*8;
        *(short8*)&Gs[n*GPAD + mm] = *(const short8*)(gsrc + r2*2048 + tid*8);
      }
    }
    __syncthreads();
    short8 af = *(const short8*)&Ap[(w*16 + l15)*APAD + kc*32 + quad*8];
    #pragma unroll
    for(int nt = 0; nt < 8; nt++){
      short8 bf = *(const short8*)&Gs[(nt*16 + l15)*GPAD + quad*8];
      acc[nt] = __builtin_amdgcn_mfma_f32_16x16x32_bf16(af, bf, acc[nt], 0, 0, 0);
    }
  }
  size_t ob = (size_t)b*SEQ*DIMN + (size_t)(i*16 + nh*8)*DIMN + (w*16 + quad*4)*16 + l15;
  #pragma unroll
  for(int nt = 0; nt < 8; nt++)
    #pragma unroll
    for(int t = 0; t < 4; t++)
      dst[ob + (size_t)nt*DIMN + t*16] = f2bu(acc[nt][t]);
}

// ---------------- all weight transposes in one launch ----------------
struct WtJob { const float* src; ushort_t* dst; int K, N, nx, tstart; };
struct WtJobs { WtJob j[7]; };
__global__ __launch_bounds__(256) void k_wtall(WtJobs jobs){
  __shared__ float tile[32][33];
  int bid = blockIdx.x;
  int ji = 0;
  #pragma unroll
  for(int i = 1; i < 7; i++) if(bid >= jobs.j[i].tstart) ji = i;
  const float* W = jobs.j[ji].src;
  ushort_t* Wt = jobs.j[ji].dst;
  int K = jobs.j[ji].K, N = jobs.j[ji].N;
  int tt = bid - jobs.j[ji].tstart;
  int n0 = (tt % jobs.j[ji].nx)*32, k0 = (tt / jobs.j[ji].nx)*32;
  int r = threadIdx.x >> 3, c4 = (threadIdx.x & 7)*4;
  float4 v = *(const float4*)(W + (size_t)(k0 + r)*N + n0 + c4);
  tile[r][c4+0] = v.x; tile[r][c4+1] = v.y; tile[r][c4+2] = v.z; tile[r][c4+3] = v.w;
  __syncthreads();
  ushort4 o;
  o.x = f2bu(tile[c4+0][r]); o.y = f2bu(tile[c4+1][r]);
  o.z = f2bu(tile[c4+2][r]); o.w = f2bu(tile[c4+3][r]);
  *(ushort4*)(Wt + (size_t)(n0 + r)*K + k0 + c4) = o;
}

// ---------------- m97-style MFMA GEMM: C(MxN) = A(MxK) @ Wt(NxK)^T ----------------
template<int BM, int BN, typename OUT>
__global__ __launch_bounds__(256) void k_gemm_mf(const ushort_t* __restrict__ A,
        const ushort_t* __restrict__ Wt, OUT* __restrict__ C, int N, int K){
  constexpr int MT = BM/32, NT = BN/32;
  constexpr int AI = BM/64, BI = BN/64;
  __shared__ __align__(16) ushort_t As[BM*32];
  __shared__ __align__(16) ushort_t Bs[BN*32];
  int tid = threadIdx.x, lane = tid & 63, w = tid >> 6;
  int l15 = lane & 15, quad = lane >> 4;
  int m0 = blockIdx.y*BM, n0 = blockIdx.x*BN;
  int wr = (w>>1)*(BM/2), wc = (w&1)*(BN/2);
  int srow = lane >> 2, scol = (lane & 3)*8;
  const ushort_t* ag[AI]; ushort_t* al[AI];
  const ushort_t* bg[BI]; ushort_t* bl[BI];
  #pragma unroll
  for(int i = 0; i < AI; i++){
    int rb = w*AI + i;
    ag[i] = A + (size_t)(m0 + rb*16 + srow)*K + scol;
    al[i] = As + rb*512 + lane*8;
  }
  #pragma unroll
  for(int i = 0; i < BI; i++){
    int rb = w*BI + i;
    bg[i] = Wt + (size_t)(n0 + rb*16 + srow)*K + scol;
    bl[i] = Bs + rb*512 + lane*8;
  }
  f32x4 acc[MT][NT];
  #pragma unroll
  for(int mt = 0; mt < MT; mt++)
    #pragma unroll
    for(int nt = 0; nt < NT; nt++)
      for(int t = 0; t < 4; t++) acc[mt][nt][t] = 0.f;
  for(int kk = 0; kk < K; kk += 32){
    __syncthreads();
    #pragma unroll
    for(int i = 0; i < AI; i++) async_cp16(ag[i] + kk, al[i]);
    #pragma unroll
    for(int i = 0; i < BI; i++) async_cp16(bg[i] + kk, bl[i]);
    __syncthreads();
    short8 af[MT], bf[NT];
    #pragma unroll
    for(int mt = 0; mt < MT; mt++) af[mt] = *(const short8*)&As[(wr + mt*16 + l15)*32 + quad*8];
    #pragma unroll
    for(int nt = 0; nt < NT; nt++) bf[nt] = *(const short8*)&Bs[(wc + nt*16 + l15)*32 + quad*8];
    #pragma unroll
    for(int mt = 0; mt < MT; mt++)
      #pragma unroll
      for(int nt = 0; nt < NT; nt++)
        acc[mt][nt] = __builtin_amdgcn_mfma_f32_16x16x32_bf16(af[mt], bf[nt], acc[mt][nt], 0, 0, 0);
  }
  #pragma unroll
  for(int mt = 0; mt < MT; mt++)
    #pragma unroll
    for(int nt = 0; nt < NT; nt++)
      #pragma unroll
      for(int t = 0; t < 4; t++)
        stv(C + (size_t)(m0 + wr + mt*16 + quad*4 + t)*N + n0 + wc + nt*16 + l15, acc[mt][nt][t]);
}

// ---------------- fused FFN up: h = silu(A@w1 * sv*sqrt(H)) * (A@w3 * su) ----------------
__global__ __launch_bounds__(256) void k_ffn12(const ushort_t* __restrict__ A,
        const ushort_t* __restrict__ W1t, const ushort_t* __restrict__ W3t,
        const float* __restrict__ su, const float* __restrict__ sv,
        ushort_t* __restrict__ H, int K){
  __shared__ __align__(16) ushort_t As[128*32];
  __shared__ __align__(16) ushort_t B1s[64*32];
  __shared__ __align__(16) ushort_t B3s[64*32];
  int tid = threadIdx.x, lane = tid & 63, w = tid >> 6;
  int l15 = lane & 15, quad = lane >> 4;
  int m0 = blockIdx.y*128, n0 = blockIdx.x*64;
  int wr = (w>>1)*64, wc = (w&1)*32;
  int srow = lane >> 2, scol = (lane & 3)*8;
  const ushort_t* ag[2]; ushort_t* al[2];
  #pragma unroll
  for(int i = 0; i < 2; i++){
    int rb = w*2 + i;
    ag[i] = A + (size_t)(m0 + rb*16 + srow)*K + scol;
    al[i] = As + rb*512 + lane*8;
  }
  const ushort_t* b1g = W1t + (size_t)(n0 + w*16 + srow)*K + scol;
  const ushort_t* b3g = W3t + (size_t)(n0 + w*16 + srow)*K + scol;
  ushort_t* b1l = B1s + w*512 + lane*8;
  ushort_t* b3l = B3s + w*512 + lane*8;
  f32x4 acc1[4][2], acc3[4][2];
  #pragma unroll
  for(int mt = 0; mt < 4; mt++)
    #pragma unroll
    for(int nt = 0; nt < 2; nt++)
      for(int t = 0; t < 4; t++){ acc1[mt][nt][t] = 0.f; acc3[mt][nt][t] = 0.f; }
  for(int kk = 0; kk < K; kk += 32){
    __syncthreads();
    async_cp16(ag[0] + kk, al[0]);
    async_cp16(ag[1] + kk, al[1]);
    async_cp16(b1g + kk, b1l);
    async_cp16(b3g + kk, b3l);
    __syncthreads();
    short8 af[4], b1f[2], b3f[2];
    #pragma unroll
    for(int mt = 0; mt < 4; mt++) af[mt] = *(const short8*)&As[(wr + mt*16 + l15)*32 + quad*8];
    #pragma unroll
    for(int nt = 0; nt < 2; nt++){
      b1f[nt] = *(const short8*)&B1s[(wc + nt*16 + l15)*32 + quad*8];
      b3f[nt] = *(const short8*)&B3s[(wc + nt*16 + l15)*32 + quad*8];
    }
    #pragma unroll
    for(int mt = 0; mt < 4; mt++)
      #pragma unroll
      for(int nt = 0; nt < 2; nt++){
        acc1[mt][nt] = __builtin_amdgcn_mfma_f32_16x16x32_bf16(af[mt], b1f[nt], acc1[mt][nt], 0, 0, 0);
        acc3[mt][nt] = __builtin_amdgcn_mfma_f32_16x16x32_bf16(af[mt], b3f[nt], acc3[mt][nt], 0, 0, 0);
      }
  }
  #pragma unroll
  for(int nt = 0; nt < 2; nt++){
    int n = n0 + wc + nt*16 + l15;
    float svv = sv[n] * 53.06599665f, suv = su[n];
    #pragma unroll
    for(int mt = 0; mt < 4; mt++)
      #pragma unroll
      for(int t = 0; t < 4; t++){
        float hpre = acc1[mt][nt][t] * svv;
        float sil = hpre / (1.f + expf(-hpre));
        float hv = sil * (acc3[mt][nt][t] * suv);
        H[(size_t)(m0 + wr + mt*16 + quad*4 + t)*HIDDEN + n] = f2bu(hv);
      }
  }
}

// ---------------- fused rotary+justnorm on q,k AND v transpose ----------------
// grid (SEQ/64, NH, B), block 256. Thread handles 16 contiguous d of one s-row.
__global__ __launch_bounds__(256) void k_qkvt(ushort_t* __restrict__ qkv,
        ushort_t* __restrict__ vto, const float* __restrict__ fc,
        const float* __restrict__ fs, const float* __restrict__ sqk){
  __shared__ ushort_t tile[64][72];
  int s0 = blockIdx.x*64, h = blockIdx.y, b = blockIdx.z;
  int tid = threadIdx.x;
  int r = tid >> 2, c = (tid & 3)*16;
  // stage V tile
  const ushort_t* vsrc = qkv + (size_t)(b*SEQ + s0 + r)*QKVS + 2048 + h*HDIM + c;
  *(short8*)&tile[r][c]     = *(const short8*)vsrc;
  *(short8*)&tile[r][c + 8] = *(const short8*)(vsrc + 8);
  // rotary + justnorm on q,k (no barrier dependency)
  size_t qb_ = (size_t)(b*SEQ + s0 + r)*QKVS + h*HDIM + c;
  short8 q0 = *(const short8*)(qkv + qb_),        q1 = *(const short8*)(qkv + qb_ + 8);
  short8 k0 = *(const short8*)(qkv + qb_ + 1024), k1 = *(const short8*)(qkv + qb_ + 1032);
  int s = s0 + r;
  float qr[16], kr[16];
  float sq = 0.f, sk = 0.f;
  #pragma unroll
  for(int j = 0; j < 16; j += 2){
    float qa = bfbits((ushort_t)(j < 8 ? q0[j] : q1[j-8]));
    float qb2 = bfbits((ushort_t)(j+1 < 8 ? q0[j+1] : q1[j-7]));
    float ka = bfbits((ushort_t)(j < 8 ? k0[j] : k1[j-8]));
    float kb2 = bfbits((ushort_t)(j+1 < 8 ? k0[j+1] : k1[j-7]));
    float co = fc[s*32 + ((c + j) >> 1)], si = fs[s*32 + ((c + j) >> 1)];
    qr[j]   = qa*co - qb2*si;  qr[j+1] = qa*si + qb2*co;
    kr[j]   = ka*co - kb2*si;  kr[j+1] = ka*si + kb2*co;
    sq += qr[j]*qr[j] + qr[j+1]*qr[j+1];
    sk += kr[j]*kr[j] + kr[j+1]*kr[j+1];
  }
  sq += __shfl_xor(sq, 1); sq += __shfl_xor(sq, 2);
  sk += __shfl_xor(sk, 1); sk += __shfl_xor(sk, 2);
  float rq = 1.f / fmaxf(sqrtf(sq), 1e-12f);
  float rk = 1.f / fmaxf(sqrtf(sk), 1e-12f);
  short8 oq0, oq1, ok0, ok1;
  #pragma unroll
  for(int j = 0; j < 8; j++){
    float s0v = sqk[h*HDIM + c + j] * 32.f;
    float s1v = sqk[h*HDIM + c + 8 + j] * 32.f;
    oq0[j] = (short)f2bu(s0v*qr[j]*rq);   oq1[j] = (short)f2bu(s1v*qr[8+j]*rq);
    ok0[j] = (short)f2bu(s0v*kr[j]*rk);   ok1[j] = (short)f2bu(s1v*kr[8+j]*rk);
  }
  *(short8*)(qkv + qb_)        = oq0;  *(short8*)(qkv + qb_ + 8)    = oq1;
  *(short8*)(qkv + qb_ + 1024) = ok0;  *(short8*)(qkv + qb_ + 1032) = ok1;
  __syncthreads();
  // write V^T
  ushort_t* dst = vto + ((size_t)(b*NHEAD + h)*HDIM + r)*SEQ + s0 + c;
  for(int j2 = 0; j2 < 16; j2 += 4){
    ushort4 o;
    o.x = tile[c+j2][r]; o.y = tile[c+j2+1][r]; o.z = tile[c+j2+2][r]; o.w = tile[c+j2+3][r];
    *(ushort4*)(dst + j2) = o;
  }
}

// ---------------- MFMA flash attention: 64 q-rows/block, fixed-max softmax, reg prefetch ----------------
#define LSTR 72
__global__ __launch_bounds__(256) void k_flash_mf(const ushort_t* __restrict__ qkv,
        const ushort_t* __restrict__ vt, ushort_t* __restrict__ out){
  int qb = blockIdx.x, h = blockIdx.y, b = blockIdx.z;
  int tid = threadIdx.x, lane = tid & 63, w = tid >> 6;
  int l15 = lane & 15, quad = lane >> 4;
  __shared__ __align__(16) ushort_t Ks[64*LSTR], Vts[64*LSTR];
  __shared__ __align__(16) ushort_t Ps[4][16*LSTR];
  size_t qkb = (size_t)b*SEQ*QKVS + h*HDIM;
  size_t ob  = (size_t)b*SEQ*DIMN + h*HDIM;
  const ushort_t* vb = vt + (size_t)(b*NHEAD + h)*HDIM*SEQ;
  short8 qf0, qf1;
  {
    const ushort_t* qrow = qkv + qkb + (size_t)(qb*64 + w*16 + l15)*QKVS;
    qf0 = *(const short8*)(qrow + quad*8);
    qf1 = *(const short8*)(qrow + 32 + quad*8);
  }
  f32x4 o_acc[4];
  #pragma unroll
  for(int g = 0; g < 4; g++){ o_acc[g][0]=0.f; o_acc[g][1]=0.f; o_acc[g][2]=0.f; o_acc[g][3]=0.f; }
  float lsum = 0.f;
  int sr = tid >> 2, sc = tid & 3;
  const ushort_t* kbase = qkv + qkb + 1024 + (size_t)sr*QKVS + sc*16;
  const ushort_t* vbase = vb + (size_t)sr*SEQ + sc*16;
  short8 kr0 = *(const short8*)kbase, kr1 = *(const short8*)(kbase + 8);
  short8 vr0 = *(const short8*)vbase, vr1 = *(const short8*)(vbase + 8);
  const float C1 = 11.54156036f;   // 8*log2(e)
  const float C2 = 11.90223409f;   // 8.25*log2(e): scores provably < 8.04
  for(int ch = 0; ch < SEQ/64; ch++){
    __syncthreads();
    *(short8*)&Ks[sr*LSTR + sc*16]      = kr0;
    *(short8*)&Ks[sr*LSTR + sc*16 + 8]  = kr1;
    *(short8*)&Vts[sr*LSTR + sc*16]     = vr0;
    *(short8*)&Vts[sr*LSTR + sc*16 + 8] = vr1;
    if(ch + 1 < SEQ/64){
      const ushort_t* kn = kbase + (size_t)(ch + 1)*64*QKVS;
      const ushort_t* vn = vbase + (ch + 1)*64;
      kr0 = *(const short8*)kn; kr1 = *(const short8*)(kn + 8);
      vr0 = *(const short8*)vn; vr1 = *(const short8*)(vn + 8);
    }
    __syncthreads();
    #pragma unroll
    for(int g = 0; g < 4; g++){
      f32x4 sa; sa[0]=0.f; sa[1]=0.f; sa[2]=0.f; sa[3]=0.f;
      short8 k0 = *(const short8*)&Ks[(g*16 + l15)*LSTR + quad*8];
      short8 k1 = *(const short8*)&Ks[(g*16 + l15)*LSTR + 32 + quad*8];
      sa = __builtin_amdgcn_mfma_f32_16x16x32_bf16(k0, qf0, sa, 0, 0, 0);
      sa = __builtin_amdgcn_mfma_f32_16x16x32_bf16(k1, qf1, sa, 0, 0, 0);
      float e0 = exp2f(fmaf(sa[0], C1, -C2));
      float e1 = exp2f(fmaf(sa[1], C1, -C2));
      float e2 = exp2f(fmaf(sa[2], C1, -C2));
      float e3 = exp2f(fmaf(sa[3], C1, -C2));
      lsum += (e0 + e1) + (e2 + e3);
      ushort4 pk;
      pk.x = f2bu_t(e0); pk.y = f2bu_t(e1); pk.z = f2bu_t(e2); pk.w = f2bu_t(e3);
      *(ushort4*)&Ps[w][l15*LSTR + g*16 + quad*4] = pk;
    }
    short8 a0 = *(const short8*)&Ps[w][l15*LSTR + quad*8];
    short8 a1 = *(const short8*)&Ps[w][l15*LSTR + 32 + quad*8];
    #pragma unroll
    for(int g = 0; g < 4; g++){
      short8 b0 = *(const short8*)&Vts[(g*16 + l15)*LSTR + quad*8];
      short8 b1 = *(const short8*)&Vts[(g*16 + l15)*LSTR + 32 + quad*8];
      o_acc[g] = __builtin_amdgcn_mfma_f32_16x16x32_bf16(a0, b0, o_acc[g], 0, 0, 0);
      o_acc[g] = __builtin_amdgcn_mfma_f32_16x16x32_bf16(a1, b1, o_acc[g], 0, 0, 0);
    }
  }
  lsum += __shfl_xor(lsum, 16);
  lsum += __shfl_xor(lsum, 32);
  #pragma unroll
  for(int t = 0; t < 4; t++){
    float inv = 1.f / __shfl(lsum, quad*4 + t);
    #pragma unroll
    for(int g = 0; g < 4; g++)
      out[ob + (size_t)(qb*64 + w*16 + quad*4 + t)*DIMN + g*16 + l15] = f2bu(o_acc[g][t] * inv);
  }
}

// ---------------- block reduce helper ----------------
__device__ __forceinline__ float blockReduceSum(float v, float* red){
  for(int off = 32; off; off >>= 1) v += __shfl_xor(v, off);
  int wid = threadIdx.x >> 6;
  if((threadIdx.x & 63) == 0) red[wid] = v;
  __syncthreads();
  float tot = red[0] + red[1] + red[2] + red[3];
  __syncthreads();
  return tot;
}

// ---------------- xo = justnorm(h + lr*(justnorm(ha) - h)), h = justnorm(x) ----------------
template<typename T1, typename T2, typename TO>
__global__ void k_rn(const T1* __restrict__ x, const T2* __restrict__ ha,
        const float* __restrict__ alpha, TO* __restrict__ xo){
  __shared__ float red[4];
  int row = blockIdx.x, tid = threadIdx.x;
  size_t base = (size_t)row * DIMN;
  float xs[4], hs[4], cs[4];
  float s1 = 0.f, s2 = 0.f;
  for(int j = 0; j < 4; j++){
    int i = tid + j*256;
    float xv = ldv(x + base + i);  xs[j] = xv; s1 += xv*xv;
    float hv = ldv(ha + base + i); hs[j] = hv; s2 += hv*hv;
  }
  s1 = blockReduceSum(s1, red);
  s2 = blockReduceSum(s2, red);
  float r1 = 1.f / fmaxf(sqrtf(s1), 1e-12f);
  float r2 = 1.f / fmaxf(sqrtf(s2), 1e-12f);
  float s3 = 0.f;
  for(int j = 0; j < 4; j++){
    int i = tid + j*256;
    float lr = fabsf(alpha[i] * 1.6f);
    float hn = xs[j] * r1;
    float cv = hn + lr*(hs[j]*r2 - hn);
    cs[j] = cv; s3 += cv*cv;
  }
  s3 = blockReduceSum(s3, red);
  float r3 = 1.f / fmaxf(sqrtf(s3), 1e-12f);
  for(int j = 0; j < 4; j++){
    int i = tid + j*256;
    stv(xo + base + i, cs[j] * r3);
  }
}

extern "C" void kernel_launch(void* const* d_in, const int* in_sizes, int n_in,
                              void* d_out, int out_size, void* d_ws, size_t ws_size,
                              hipStream_t stream){
  const float* x   = (const float*)d_in[0];
  const float* fc  = (const float*)d_in[1];
  const float* fs  = (const float*)d_in[2];
  const float* ada = (const float*)d_in[3];
  const float* wq  = (const float*)d_in[4];
  const float* wk  = (const float*)d_in[5];
  const float* wv  = (const float*)d_in[6];
  const float* wo  = (const float*)d_in[7];
  const float* sqk = (const float*)d_in[8];
  const float* w1  = (const float*)d_in[9];
  const float* w2  = (const float*)d_in[10];
  const float* w3  = (const float*)d_in[11];
  const float* su  = (const float*)d_in[12];
  const float* sv  = (const float*)d_in[13];
  const float* pw  = (const float*)d_in[14];
  const float* pb  = (const float*)d_in[15];
  const float* aal = (const float*)d_in[16];
  const float* mal = (const float*)d_in[17];
  float* out = (float*)d_out;

  const size_t MM = (size_t)DIMN*DIMN;
  const size_t HM = (size_t)HIDDEN*DIMN;
  const size_t F  = (size_t)ROWS*DIMN;
  char* wsb = (char*)d_ws;
  float* t = (float*)wsb;                      // 1024
  ushort_t* Gpk = (ushort_t*)(wsb + 16384);    // 4*8*8192 el
  ushort_t* wqT = Gpk + 262144;                // QKV weights contiguous -> [3072][1024]
  ushort_t* wkT = wqT + MM;
  ushort_t* wvT = wkT + MM;
  ushort_t* woT = wvT + MM;
  ushort_t* w1T = woT + MM;                    // [2816][1024]
  ushort_t* w3T = w1T + HM;
  ushort_t* w2T = w3T + HM;                    // [1024][2816]
  ushort_t* P1  = w2T + HM;                    // xmod -> attnO -> x1
  ushort_t* QKV = P1 + F;                      // [ROWS][3072]; later Ha/M2/Hm slots
  ushort_t* Ha  = QKV;                         // h_a   [ROWS][1024]
  ushort_t* M2  = QKV + F;                     // xmod2 [ROWS][1024]
  ushort_t* Hm  = QKV + 2*F;                   // h_m   [ROWS][1024]
  ushort_t* a1  = QKV + 3*F;                   // [ROWS][2816]; aliases Vt
  ushort_t* Vt  = a1;                          // [B][NH][64][SEQ]

  dim3 blk(256);

  k_time<<<dim3(1024), dim3(64), 0, stream>>>(ada, pw, pb, t);
  k_gp<<<dim3(4,8), blk, 0, stream>>>(t, Gpk);

  WtJobs jobs;
  jobs.j[0] = {wq, wqT, DIMN, DIMN, 32, 0};
  jobs.j[1] = {wk, wkT, DIMN, DIMN, 32, 1024};
  jobs.j[2] = {wv, wvT, DIMN, DIMN, 32, 2048};
  jobs.j[3] = {wo, woT, DIMN, DIMN, 32, 3072};
  jobs.j[4] = {w1, w1T, DIMN, HIDDEN, HIDDEN/32, 4096};
  jobs.j[5] = {w3, w3T, DIMN, HIDDEN, HIDDEN/32, 4096 + 2816};
  jobs.j[6] = {w2, w2T, HIDDEN, DIMN, 32, 4096 + 5632};
  k_wtall<<<dim3(12544), blk, 0, stream>>>(jobs);

  // attention branch
  k_modmf<float><<<dim3(2,128,BATCH), blk, 0, stream>>>(x, Gpk, P1);
  k_gemm_mf<128,128,ushort_t><<<dim3(24,32), blk, 0, stream>>>(P1, wqT, QKV, QKVS, DIMN);
  k_qkvt<<<dim3(SEQ/64,NHEAD,BATCH), blk, 0, stream>>>(QKV, Vt, fc, fs, sqk);
  k_flash_mf<<<dim3(SEQ/64,NHEAD,BATCH), blk, 0, stream>>>(QKV, Vt, P1);
  k_gemm_mf<128,64,ushort_t><<<dim3(16,32), blk, 0, stream>>>(P1, woT, Ha, DIMN, DIMN);
  k_rn<float,ushort_t,ushort_t><<<dim3(ROWS), blk, 0, stream>>>(x, Ha, aal, P1);

  // FFN branch (single chunk)
  k_modmf<ushort_t><<<dim3(2,128,BATCH), blk, 0, stream>>>(P1, Gpk + 131072, M2);
  k_ffn12<<<dim3(HIDDEN/64,ROWS/128), blk, 0, stream>>>(M2, w1T, w3T, su, sv, a1, DIMN);
  k_gemm_mf<128,64,ushort_t><<<dim3(16,32), blk, 0, stream>>>(a1, w2T, Hm, DIMN, HIDDEN);
  k_rn<ushort_t,ushort_t,float><<<dim3(ROWS), blk, 0, stream>>>(P1, Hm, mal, out);
}